// Round 6
// baseline (293.758 us; speedup 1.0000x reference)
//
#include <hip/hip_runtime.h>
#include <hip/hip_bf16.h>
#include <cstdint>
#include <type_traits>

// Problem constants (B=2, L=1024)
#define T_TOK 2048   // B*L tokens
#define DM    1024   // d_model
#define DI    2048   // d_inner
#define NST   16     // d_state
#define DTR   64     // dt_rank
#define XD    96     // dt_rank + 2*d_state
#define NCH   32     // scan chunks
#define CL    32     // chunk length (NCH*CL = 1024)

typedef float  f32x4  __attribute__((ext_vector_type(4)));
typedef __bf16 bf16x8 __attribute__((ext_vector_type(8)));

__device__ __forceinline__ float bf2f(ushort u) {
  union { float f; uint32_t i; } c; c.i = ((uint32_t)u) << 16; return c.f;
}
__device__ __forceinline__ float lo16(uint32_t u) {
  union { float f; uint32_t i; } c; c.i = u << 16; return c.f;
}
__device__ __forceinline__ float hi16(uint32_t u) {
  union { float f; uint32_t i; } c; c.i = u & 0xFFFF0000u; return c.f;
}
__device__ __forceinline__ ushort f2bf(float f) {
  union { float f; uint32_t i; } c; c.f = f;
  uint32_t r = c.i + 0x7FFF + ((c.i >> 16) & 1);  // RNE
  return (ushort)(r >> 16);
}
__device__ __forceinline__ void async_ld16(const void* g, void* l) {
  __builtin_amdgcn_global_load_lds(
      (const __attribute__((address_space(1))) void*)g,
      (__attribute__((address_space(3))) void*)l, 16, 0, 0);
}

// ============ prep: weights fp32->bf16 (blocks 0..6463) + LN (6464..8511) ==
#define CAST_BLK 6464   // nWtot/1024
__global__ __launch_bounds__(256) void k_prep(
    const float* __restrict__ s0, int n0, const float* __restrict__ s1, int n1,
    const float* __restrict__ s2, int n2, const float* __restrict__ s3, int n3,
    ushort* __restrict__ dst,
    const float* __restrict__ x, const float* __restrict__ g,
    const float* __restrict__ b, ushort* __restrict__ xn) {
  __shared__ float s_sum[4], s_sq[4];
  if (blockIdx.x < CAST_BLK) {
    int i = (blockIdx.x * 256 + threadIdx.x) * 4;
    const float* src; int base;
    if (i < n0)                { src = s0; base = 0; }
    else if (i < n0 + n1)      { src = s1; base = n0; }
    else if (i < n0 + n1 + n2) { src = s2; base = n0 + n1; }
    else                       { src = s3; base = n0 + n1 + n2; }
    float4 v = *(const float4*)(src + (i - base));
    ushort4 o; o.x = f2bf(v.x); o.y = f2bf(v.y); o.z = f2bf(v.z); o.w = f2bf(v.w);
    *(ushort4*)(dst + i) = o;
    return;
  }
  int t = blockIdx.x - CAST_BLK;
  const float* row = x + (size_t)t * DM;
  int i0 = threadIdx.x * 4;
  float4 v = *(const float4*)(row + i0);
  float sum = v.x + v.y + v.z + v.w;
  float sq  = v.x*v.x + v.y*v.y + v.z*v.z + v.w*v.w;
  for (int o = 32; o > 0; o >>= 1) {
    sum += __shfl_down(sum, o, 64);
    sq  += __shfl_down(sq,  o, 64);
  }
  int wid = threadIdx.x >> 6;
  if ((threadIdx.x & 63) == 0) { s_sum[wid] = sum; s_sq[wid] = sq; }
  __syncthreads();
  float ts = s_sum[0] + s_sum[1] + s_sum[2] + s_sum[3];
  float tq = s_sq[0]  + s_sq[1]  + s_sq[2]  + s_sq[3];
  float mu   = ts * (1.f / DM);
  float var  = tq * (1.f / DM) - mu * mu;
  float rinv = rsqrtf(var + 1e-5f);
  float4 gr = *(const float4*)(g + i0);
  float4 br = *(const float4*)(b + i0);
  ushort4 o;
  o.x = f2bf((v.x - mu) * rinv * gr.x + br.x);
  o.y = f2bf((v.y - mu) * rinv * gr.y + br.y);
  o.z = f2bf((v.z - mu) * rinv * gr.z + br.z);
  o.w = f2bf((v.w - mu) * rinv * gr.w + br.w);
  *(ushort4*)(xn + (size_t)t * DM + i0) = o;
}

// ====== 128x128 NT GEMM, async global->LDS (m97 pattern), stride-32 LDS ====
// EPI: 0 = +bias ; 1 = none ; 2 = +bias softplus ; 3 = +bias +residual
template <int EPI, typename OT>
__global__ __launch_bounds__(256) void k_gemm128(
    const ushort* __restrict__ A, int lda,
    const ushort* __restrict__ Bm, int ldb,
    int N, int K,
    const float* __restrict__ bias,
    const float* __restrict__ resid, int ldr,
    OT* __restrict__ C, int ldc) {
  __shared__ ushort lA[128 * 32];
  __shared__ ushort lB[128 * 32];
  const int tile_m = blockIdx.x * 128;
  const int tile_n = blockIdx.y * 128;
  const int tid  = threadIdx.x;
  const int lane = tid & 63;
  const int w    = tid >> 6;
  const int wm = (w & 1) * 64;
  const int wn = (w >> 1) * 64;
  f32x4 acc[4][4];
#pragma unroll
  for (int i = 0; i < 4; i++)
#pragma unroll
    for (int j = 0; j < 4; j++) acc[i][j] = (f32x4){0.f, 0.f, 0.f, 0.f};

  // async staging: wave w instr covers rows w*16+lane/4; lane col (lane&3)*8
  const int srow = w * 16 + (lane >> 2);
  const int scol = (lane & 3) * 8;
  const ushort* agA0 = A + (size_t)(tile_m + srow) * lda + scol;
  const ushort* agA1 = A + (size_t)(tile_m + srow + 64) * lda + scol;
  int bn0 = tile_n + srow;      if (bn0 > N - 1) bn0 = N - 1;
  int bn1 = tile_n + srow + 64; if (bn1 > N - 1) bn1 = N - 1;
  const ushort* agB0 = Bm + (size_t)bn0 * ldb + scol;
  const ushort* agB1 = Bm + (size_t)bn1 * ldb + scol;
  ushort* ldsA0 = lA + (w * 16) * 32;        // wave-uniform bases
  ushort* ldsA1 = lA + (w * 16 + 64) * 32;
  ushort* ldsB0 = lB + (w * 16) * 32;
  ushort* ldsB1 = lB + (w * 16 + 64) * 32;
  const int fm = lane & 15;
  const int fq = (lane >> 4) * 8;

  for (int k0 = 0; k0 < K; k0 += 32) {
    __syncthreads();
    async_ld16(agA0 + k0, ldsA0);
    async_ld16(agA1 + k0, ldsA1);
    async_ld16(agB0 + k0, ldsB0);
    async_ld16(agB1 + k0, ldsB1);
    __syncthreads();   // drains vmcnt -> LDS valid
    bf16x8 af[4], bfr[4];
#pragma unroll
    for (int i = 0; i < 4; i++) {
      af[i]  = *(const bf16x8*)(lA + (wm + 16 * i + fm) * 32 + fq);
      bfr[i] = *(const bf16x8*)(lB + (wn + 16 * i + fm) * 32 + fq);
    }
#pragma unroll
    for (int i = 0; i < 4; i++)
#pragma unroll
      for (int j = 0; j < 4; j++)
        acc[i][j] = __builtin_amdgcn_mfma_f32_16x16x32_bf16(af[i], bfr[j],
                                                            acc[i][j], 0, 0, 0);
  }

#pragma unroll
  for (int i = 0; i < 4; i++) {
#pragma unroll
    for (int j = 0; j < 4; j++) {
      int col = tile_n + wn + 16 * j + (lane & 15);
      if (col >= N) continue;
      int row0 = tile_m + wm + 16 * i + (lane >> 4) * 4;
      float bv = (EPI == 1) ? 0.f : bias[col];
#pragma unroll
      for (int r = 0; r < 4; r++) {
        int row = row0 + r;
        float v = acc[i][j][r] + bv;
        if (EPI == 2) v = (v > 20.f) ? v : log1pf(__expf(v));
        if (EPI == 3) v += resid[(size_t)row * ldr + col];
        if constexpr (std::is_same<OT, float>::value)
          C[(size_t)row * ldc + col] = v;
        else
          C[(size_t)row * ldc + col] = f2bf(v);
      }
    }
  }
}

// ------------- 64x64 NT GEMM, async staging (small N / small K) ------------
template <int EPI, typename OT>
__global__ __launch_bounds__(256) void k_gemm(
    const ushort* __restrict__ A, int lda,
    const ushort* __restrict__ Bm, int ldb,
    int N, int K,
    const float* __restrict__ bias,
    const float* __restrict__ resid, int ldr,
    OT* __restrict__ C, int ldc) {
  __shared__ ushort lA[64 * 32];
  __shared__ ushort lB[64 * 32];
  const int tile_m = blockIdx.x * 64;
  const int tile_n = blockIdx.y * 64;
  const int lane = threadIdx.x & 63;
  const int w    = threadIdx.x >> 6;
  const int wm = (w & 1) * 32;
  const int wn = (w >> 1) * 32;
  f32x4 acc[2][2];
#pragma unroll
  for (int i = 0; i < 2; i++)
#pragma unroll
    for (int j = 0; j < 2; j++) acc[i][j] = (f32x4){0.f, 0.f, 0.f, 0.f};

  const int srow = w * 16 + (lane >> 2);
  const int scol = (lane & 3) * 8;
  const ushort* ag = A + (size_t)(tile_m + srow) * lda + scol;
  int brow = tile_n + srow; if (brow > N - 1) brow = N - 1;
  const ushort* bg = Bm + (size_t)brow * ldb + scol;
  ushort* ldsA = lA + (w * 16) * 32;
  ushort* ldsB = lB + (w * 16) * 32;

  const int fm = lane & 15;
  const int fq = (lane >> 4) * 8;

  for (int k0 = 0; k0 < K; k0 += 32) {
    __syncthreads();
    async_ld16(ag + k0, ldsA);
    async_ld16(bg + k0, ldsB);
    __syncthreads();
    bf16x8 a0 = *(const bf16x8*)(lA + (wm +  0 + fm) * 32 + fq);
    bf16x8 a1 = *(const bf16x8*)(lA + (wm + 16 + fm) * 32 + fq);
    bf16x8 b0 = *(const bf16x8*)(lB + (wn +  0 + fm) * 32 + fq);
    bf16x8 b1 = *(const bf16x8*)(lB + (wn + 16 + fm) * 32 + fq);
    acc[0][0] = __builtin_amdgcn_mfma_f32_16x16x32_bf16(a0, b0, acc[0][0], 0, 0, 0);
    acc[0][1] = __builtin_amdgcn_mfma_f32_16x16x32_bf16(a0, b1, acc[0][1], 0, 0, 0);
    acc[1][0] = __builtin_amdgcn_mfma_f32_16x16x32_bf16(a1, b0, acc[1][0], 0, 0, 0);
    acc[1][1] = __builtin_amdgcn_mfma_f32_16x16x32_bf16(a1, b1, acc[1][1], 0, 0, 0);
  }

#pragma unroll
  for (int mi = 0; mi < 2; mi++) {
#pragma unroll
    for (int ni = 0; ni < 2; ni++) {
      int col = tile_n + wn + ni * 16 + (lane & 15);
      if (col >= N) continue;
      int row0 = tile_m + wm + mi * 16 + (lane >> 4) * 4;
      float bv2 = (EPI == 1) ? 0.f : bias[col];
#pragma unroll
      for (int r = 0; r < 4; r++) {
        int row = row0 + r;
        float v = acc[mi][ni][r] + bv2;
        if (EPI == 2) v = (v > 20.f) ? v : log1pf(__expf(v));
        if (EPI == 3) v += resid[(size_t)row * ldr + col];
        if constexpr (std::is_same<OT, float>::value)
          C[(size_t)row * ldc + col] = v;
        else
          C[(size_t)row * ldc + col] = f2bf(v);
      }
    }
  }
}

// ------------- depthwise causal conv (k=4) + SiLU, 8 channels/thread -------
__global__ __launch_bounds__(256) void k_conv(const ushort* __restrict__ xz,
                                              const float* __restrict__ cw,
                                              const float* __restrict__ cb,
                                              ushort* __restrict__ xc) {
  int idx = blockIdx.x * 256 + threadIdx.x;   // over T_TOK * DI/8
  int d8 = (idx & 255) * 8;
  int t  = idx >> 8;
  int l  = t & 1023;
  float acc[8];
  {
    float4 c0 = *(const float4*)(cb + d8);
    float4 c1 = *(const float4*)(cb + d8 + 4);
    acc[0]=c0.x; acc[1]=c0.y; acc[2]=c0.z; acc[3]=c0.w;
    acc[4]=c1.x; acc[5]=c1.y; acc[6]=c1.z; acc[7]=c1.w;
  }
  float wk[8][4];
#pragma unroll
  for (int j = 0; j < 8; j++) {
    float4 wv = *(const float4*)(cw + (d8 + j) * 4);
    wk[j][0]=wv.x; wk[j][1]=wv.y; wk[j][2]=wv.z; wk[j][3]=wv.w;
  }
#pragma unroll
  for (int k = 0; k < 4; k++) {
    int lk = l + k - 3;
    if (lk >= 0) {
      uint4 raw = *(const uint4*)&xz[(size_t)(t + k - 3) * 4096 + d8];
      float v[8];
      v[0]=lo16(raw.x); v[1]=hi16(raw.x); v[2]=lo16(raw.y); v[3]=hi16(raw.y);
      v[4]=lo16(raw.z); v[5]=hi16(raw.z); v[6]=lo16(raw.w); v[7]=hi16(raw.w);
#pragma unroll
      for (int j = 0; j < 8; j++) acc[j] += v[j] * wk[j][k];
    }
  }
  uint32_t o[4];
#pragma unroll
  for (int p = 0; p < 4; p++) {
    float a0 = acc[2*p],   s0 = a0 / (1.f + __expf(-a0));
    float a1 = acc[2*p+1], s1 = a1 / (1.f + __expf(-a1));
    o[p] = (uint32_t)f2bf(s0) | ((uint32_t)f2bf(s1) << 16);
  }
  uint4 st = {o[0], o[1], o[2], o[3]};
  *(uint4*)&xc[(size_t)t * DI + d8] = st;
}

// ================= selective scan: chunked 3-phase (chunk=32) ==============
__global__ __launch_bounds__(256) void k_scan1(
    const ushort* __restrict__ dt,
    const ushort* __restrict__ xc,
    const ushort* __restrict__ xdbl,
    const float*  __restrict__ alog,
    float* __restrict__ P,
    float* __restrict__ Q)
{
  const int tid = threadIdx.x;
  const int d0  = blockIdx.x * 256;
  const int d   = d0 + tid;
  const int b   = blockIdx.y;
  const int c   = blockIdx.z;
  float Ac[16];
#pragma unroll
  for (int s = 0; s < 16; s++) Ac[s] = -__expf(alog[d * 16 + s]);
  float h[16];
#pragma unroll
  for (int s = 0; s < 16; s++) h[s] = 0.f;
  float sumdt = 0.f;
  __shared__ ushort s_dt[16][256];
  __shared__ ushort s_x [16][256];
  __shared__ ushort s_B [16][16];
  const int tok_c = b * 1024 + c * CL;
  for (int st = 0; st < CL; st += 16) {
    __syncthreads();
#pragma unroll
    for (int p = 0; p < 2; p++) {
      int idx = p * 256 + tid;
      int row = idx >> 5, col = (idx & 31) * 8;
      size_t goff = (size_t)(tok_c + st + row) * DI + d0 + col;
      *(uint4*)&s_dt[row][col] = *(const uint4*)&dt[goff];
      *(uint4*)&s_x [row][col] = *(const uint4*)&xc[goff];
    }
    s_B[tid >> 4][tid & 15] =
        xdbl[(size_t)(tok_c + st + (tid >> 4)) * XD + DTR + (tid & 15)];
    __syncthreads();
    for (int t = 0; t < 16; t++) {
      float dtv = bf2f(s_dt[t][tid]);
      float xv  = bf2f(s_x [t][tid]);
      float dtx = dtv * xv;
      sumdt += dtv;
      uint4 b0 = *(const uint4*)&s_B[t][0];
      uint4 b1 = *(const uint4*)&s_B[t][8];
      float Bf[16];
      Bf[0]=lo16(b0.x); Bf[1]=hi16(b0.x); Bf[2]=lo16(b0.y); Bf[3]=hi16(b0.y);
      Bf[4]=lo16(b0.z); Bf[5]=hi16(b0.z); Bf[6]=lo16(b0.w); Bf[7]=hi16(b0.w);
      Bf[8]=lo16(b1.x); Bf[9]=hi16(b1.x); Bf[10]=lo16(b1.y); Bf[11]=hi16(b1.y);
      Bf[12]=lo16(b1.z); Bf[13]=hi16(b1.z); Bf[14]=lo16(b1.w); Bf[15]=hi16(b1.w);
#pragma unroll
      for (int s = 0; s < 16; s++) {
        float dA = __expf(dtv * Ac[s]);
        h[s] = dA * h[s] + dtx * Bf[s];
      }
    }
  }
  size_t base = (((size_t)(b * NCH + c)) * 2048 + d) * 16;
#pragma unroll
  for (int s = 0; s < 16; s++) {
    P[base + s] = __expf(sumdt * Ac[s]);
    Q[base + s] = h[s];
  }
}

__global__ __launch_bounds__(256) void k_carry(const float* __restrict__ P,
                                               float* __restrict__ Q) {
  int tid = blockIdx.x * 256 + threadIdx.x;   // 65536 = 2*2048*16
  int ds = tid & 32767, b = tid >> 15;
  float Pc[NCH], Qc[NCH];
#pragma unroll
  for (int c = 0; c < NCH; c++) {
    size_t idx = ((size_t)(b * NCH + c)) * 32768 + ds;
    Pc[c] = P[idx];
    Qc[c] = Q[idx];
  }
  float H = 0.f;
#pragma unroll
  for (int c = 0; c < NCH; c++) {
    size_t idx = ((size_t)(b * NCH + c)) * 32768 + ds;
    Q[idx] = H;
    H = Pc[c] * H + Qc[c];
  }
}

__global__ __launch_bounds__(256) void k_scan2(
    const ushort* __restrict__ dt,
    const ushort* __restrict__ xc,
    const ushort* __restrict__ xdbl,
    const ushort* __restrict__ xz,
    const float*  __restrict__ alog,
    const float*  __restrict__ Dp,
    const float*  __restrict__ Hin,
    ushort* __restrict__ yg)
{
  const int tid = threadIdx.x;
  const int d0  = blockIdx.x * 256;
  const int d   = d0 + tid;
  const int b   = blockIdx.y;
  const int c   = blockIdx.z;
  float Ac[16];
#pragma unroll
  for (int s = 0; s < 16; s++) Ac[s] = -__expf(alog[d * 16 + s]);
  float h[16];
  size_t hbase = (((size_t)(b * NCH + c)) * 2048 + d) * 16;
#pragma unroll
  for (int s = 0; s < 16; s++) h[s] = Hin[hbase + s];
  const float Dv = Dp[d];
  __shared__ ushort s_dt[16][256];
  __shared__ ushort s_x [16][256];
  __shared__ ushort s_z [16][256];
  __shared__ ushort s_B [16][16];
  __shared__ ushort s_C [16][16];
  const int tok_c = b * 1024 + c * CL;
  for (int st = 0; st < CL; st += 16) {
    __syncthreads();
#pragma unroll
    for (int p = 0; p < 2; p++) {
      int idx = p * 256 + tid;
      int row = idx >> 5, col = (idx & 31) * 8;
      size_t tok = (size_t)(tok_c + st + row);
      *(uint4*)&s_dt[row][col] = *(const uint4*)&dt[tok * DI + d0 + col];
      *(uint4*)&s_x [row][col] = *(const uint4*)&xc[tok * DI + d0 + col];
      *(uint4*)&s_z [row][col] = *(const uint4*)&xz[tok * 4096 + DI + d0 + col];
    }
    {
      int t = tid >> 4, s = tid & 15;
      size_t tok = (size_t)(tok_c + st + t);
      s_B[t][s] = xdbl[tok * XD + DTR + s];
      s_C[t][s] = xdbl[tok * XD + DTR + NST + s];
    }
    __syncthreads();
    for (int t = 0; t < 16; t++) {
      float dtv = bf2f(s_dt[t][tid]);
      float xv  = bf2f(s_x [t][tid]);
      float zv  = bf2f(s_z [t][tid]);
      float dtx = dtv * xv;
      uint4 b0 = *(const uint4*)&s_B[t][0];
      uint4 b1 = *(const uint4*)&s_B[t][8];
      uint4 c0 = *(const uint4*)&s_C[t][0];
      uint4 c1 = *(const uint4*)&s_C[t][8];
      float Bf[16], Cf[16];
      Bf[0]=lo16(b0.x); Bf[1]=hi16(b0.x); Bf[2]=lo16(b0.y); Bf[3]=hi16(b0.y);
      Bf[4]=lo16(b0.z); Bf[5]=hi16(b0.z); Bf[6]=lo16(b0.w); Bf[7]=hi16(b0.w);
      Bf[8]=lo16(b1.x); Bf[9]=hi16(b1.x); Bf[10]=lo16(b1.y); Bf[11]=hi16(b1.y);
      Bf[12]=lo16(b1.z); Bf[13]=hi16(b1.z); Bf[14]=lo16(b1.w); Bf[15]=hi16(b1.w);
      Cf[0]=lo16(c0.x); Cf[1]=hi16(c0.x); Cf[2]=lo16(c0.y); Cf[3]=hi16(c0.y);
      Cf[4]=lo16(c0.z); Cf[5]=hi16(c0.z); Cf[6]=lo16(c0.w); Cf[7]=hi16(c0.w);
      Cf[8]=lo16(c1.x); Cf[9]=hi16(c1.x); Cf[10]=lo16(c1.y); Cf[11]=hi16(c1.y);
      Cf[12]=lo16(c1.z); Cf[13]=hi16(c1.z); Cf[14]=lo16(c1.w); Cf[15]=hi16(c1.w);
      float y = 0.f;
#pragma unroll
      for (int s = 0; s < 16; s++) {
        float dA = __expf(dtv * Ac[s]);
        h[s] = dA * h[s] + dtx * Bf[s];
        y += h[s] * Cf[s];
      }
      y = (y + Dv * xv) * (zv / (1.f + __expf(-zv)));
      yg[(size_t)(tok_c + st + t) * DI + d] = f2bf(y);
    }
  }
}

extern "C" void kernel_launch(void* const* d_in, const int* in_sizes, int n_in,
                              void* d_out, int out_size, void* d_ws, size_t ws_size,
                              hipStream_t stream) {
  const float* x     = (const float*)d_in[0];
  const float* ln_g  = (const float*)d_in[1];
  const float* ln_b  = (const float*)d_in[2];
  const float* W_in  = (const float*)d_in[3];
  const float* b_in  = (const float*)d_in[4];
  const float* cw    = (const float*)d_in[5];
  const float* cb    = (const float*)d_in[6];
  const float* W_x   = (const float*)d_in[7];
  const float* W_dt  = (const float*)d_in[8];
  const float* b_dt  = (const float*)d_in[9];
  const float* A_log = (const float*)d_in[10];
  const float* Dp    = (const float*)d_in[11];
  const float* W_out = (const float*)d_in[12];
  const float* b_out = (const float*)d_in[13];
  float* out = (float*)d_out;

  const int nWin  = 2 * DI * DM;
  const int nWx   = XD * DI;
  const int nWdt  = DI * DTR;
  const int nWout = DM * DI;
  const int nWtot = nWin + nWx + nWdt + nWout;   // 6,619,136 = 6464*1024

  char* ws = (char*)d_ws;
  ushort* wbf  = (ushort*)(ws);
  ushort* wWin  = wbf;
  ushort* wWx   = wbf + nWin;
  ushort* wWdt  = wbf + nWin + nWx;
  ushort* wWout = wbf + nWin + nWx + nWdt;
  ushort* xn   = (ushort*)(ws + 16u * 1024 * 1024);   // 4 MB
  ushort* xz   = (ushort*)(ws + 24u * 1024 * 1024);   // 16 MB
  ushort* xc   = (ushort*)(ws + 40u * 1024 * 1024);   // 8 MB
  ushort* xdbl = (ushort*)(ws + 48u * 1024 * 1024);   // 0.4 MB
  ushort* dtb  = (ushort*)(ws + 52u * 1024 * 1024);   // 8 MB
  ushort* ygb  = (ushort*)(ws + 60u * 1024 * 1024);   // 8 MB
  float*  Pbuf = (float*)(ws + 68u * 1024 * 1024);    // 8 MB (2*32*2048*16 f32)
  float*  Qbuf = (float*)(ws + 76u * 1024 * 1024);    // 8 MB (total 84 MB)

  k_prep<<<CAST_BLK + T_TOK, 256, 0, stream>>>(W_in, nWin, W_x, nWx, W_dt, nWdt,
                                               W_out, nWout, wbf,
                                               x, ln_g, ln_b, xn);
  // xz = xn @ W_in^T + b_in            [2048 x 4096], K=1024
  k_gemm128<0, ushort><<<dim3(16, 32), 256, 0, stream>>>(xn, DM, wWin, DM,
                                                         2 * DI, DM, b_in,
                                                         nullptr, 0, xz, 2 * DI);
  k_conv<<<(T_TOK * DI / 8) / 256, 256, 0, stream>>>(xz, cw, cb, xc);
  // xdbl = xc @ W_x^T                  [2048 x 96], K=2048
  k_gemm<1, ushort><<<dim3(32, 2), 256, 0, stream>>>(xc, DI, wWx, DI, XD, DI,
                                                     nullptr, nullptr, 0, xdbl, XD);
  // dt = softplus(xdbl[:, :64] @ W_dt^T + b_dt)   [2048 x 2048], K=64
  k_gemm<2, ushort><<<dim3(32, 32), 256, 0, stream>>>(xdbl, XD, wWdt, DTR, DI, DTR,
                                                      b_dt, nullptr, 0, dtb, DI);
  // chunked selective scan (32 chunks of 32 steps)
  k_scan1<<<dim3(8, 2, NCH), 256, 0, stream>>>(dtb, xc, xdbl, A_log, Pbuf, Qbuf);
  k_carry<<<256, 256, 0, stream>>>(Pbuf, Qbuf);
  k_scan2<<<dim3(8, 2, NCH), 256, 0, stream>>>(dtb, xc, xdbl, xz, A_log, Dp,
                                               Qbuf, ygb);
  // out = ygb @ W_out^T + b_out + x    [2048 x 1024], K=2048
  k_gemm128<3, float><<<dim3(16, 8), 256, 0, stream>>>(ygb, DI, wWout, DI, DM, DI,
                                                       b_out, x, DM, out, DM);
}

// Round 7
// 271.958 us; speedup vs baseline: 1.0802x; 1.0802x over previous
//
#include <hip/hip_runtime.h>
#include <hip/hip_bf16.h>
#include <cstdint>
#include <type_traits>

// Problem constants (B=2, L=1024)
#define T_TOK 2048   // B*L tokens
#define DM    1024   // d_model
#define DI    2048   // d_inner
#define NST   16     // d_state
#define DTR   64     // dt_rank
#define XD    96     // dt_rank + 2*d_state
#define NCH   32     // scan chunks
#define CL    32     // chunk length (NCH*CL = 1024)

typedef float  f32x4  __attribute__((ext_vector_type(4)));
typedef __bf16 bf16x8 __attribute__((ext_vector_type(8)));

__device__ __forceinline__ float bf2f(ushort u) {
  union { float f; uint32_t i; } c; c.i = ((uint32_t)u) << 16; return c.f;
}
__device__ __forceinline__ float lo16(uint32_t u) {
  union { float f; uint32_t i; } c; c.i = u << 16; return c.f;
}
__device__ __forceinline__ float hi16(uint32_t u) {
  union { float f; uint32_t i; } c; c.i = u & 0xFFFF0000u; return c.f;
}
__device__ __forceinline__ ushort f2bf(float f) {
  union { float f; uint32_t i; } c; c.f = f;
  uint32_t r = c.i + 0x7FFF + ((c.i >> 16) & 1);  // RNE
  return (ushort)(r >> 16);
}

// ============ prep: weights fp32->bf16 (blocks 0..6463) + LN (6464..8511) ==
#define CAST_BLK 6464   // nWtot/1024
__global__ __launch_bounds__(256) void k_prep(
    const float* __restrict__ s0, int n0, const float* __restrict__ s1, int n1,
    const float* __restrict__ s2, int n2, const float* __restrict__ s3, int n3,
    ushort* __restrict__ dst,
    const float* __restrict__ x, const float* __restrict__ g,
    const float* __restrict__ b, ushort* __restrict__ xn) {
  __shared__ float s_sum[4], s_sq[4];
  if (blockIdx.x < CAST_BLK) {
    int i = (blockIdx.x * 256 + threadIdx.x) * 4;
    const float* src; int base;
    if (i < n0)                { src = s0; base = 0; }
    else if (i < n0 + n1)      { src = s1; base = n0; }
    else if (i < n0 + n1 + n2) { src = s2; base = n0 + n1; }
    else                       { src = s3; base = n0 + n1 + n2; }
    float4 v = *(const float4*)(src + (i - base));
    ushort4 o; o.x = f2bf(v.x); o.y = f2bf(v.y); o.z = f2bf(v.z); o.w = f2bf(v.w);
    *(ushort4*)(dst + i) = o;
    return;
  }
  int t = blockIdx.x - CAST_BLK;
  const float* row = x + (size_t)t * DM;
  int i0 = threadIdx.x * 4;
  float4 v = *(const float4*)(row + i0);
  float sum = v.x + v.y + v.z + v.w;
  float sq  = v.x*v.x + v.y*v.y + v.z*v.z + v.w*v.w;
  for (int o = 32; o > 0; o >>= 1) {
    sum += __shfl_down(sum, o, 64);
    sq  += __shfl_down(sq,  o, 64);
  }
  int wid = threadIdx.x >> 6;
  if ((threadIdx.x & 63) == 0) { s_sum[wid] = sum; s_sq[wid] = sq; }
  __syncthreads();
  float ts = s_sum[0] + s_sum[1] + s_sum[2] + s_sum[3];
  float tq = s_sq[0]  + s_sq[1]  + s_sq[2]  + s_sq[3];
  float mu   = ts * (1.f / DM);
  float var  = tq * (1.f / DM) - mu * mu;
  float rinv = rsqrtf(var + 1e-5f);
  float4 gr = *(const float4*)(g + i0);
  float4 br = *(const float4*)(b + i0);
  ushort4 o;
  o.x = f2bf((v.x - mu) * rinv * gr.x + br.x);
  o.y = f2bf((v.y - mu) * rinv * gr.y + br.y);
  o.z = f2bf((v.z - mu) * rinv * gr.z + br.z);
  o.w = f2bf((v.w - mu) * rinv * gr.w + br.w);
  *(ushort4*)(xn + (size_t)t * DM + i0) = o;
}

// ====== 128xTN NT GEMM, register-prefetch staging, LW=40 padded LDS ========
// TN in {128, 64}. grid = (M/128, N/TN). 4 waves: wave w -> rows wm..wm+63,
// cols wn..wn+TN/2-1. EPI: 0 +bias ; 1 none ; 2 +bias softplus ; 3 +bias+res.
template <int EPI, typename OT, int TN>
__global__ __launch_bounds__(256) void k_gemm128(
    const ushort* __restrict__ A, int lda,
    const ushort* __restrict__ Bm, int ldb,
    int N, int K,
    const float* __restrict__ bias,
    const float* __restrict__ resid, int ldr,
    OT* __restrict__ C, int ldc) {
  constexpr int LW = 40;
  constexpr int TNW = TN / 2;       // per-wave N extent
  constexpr int NJ  = TNW / 16;     // accs in N dir
  __shared__ ushort lA[128 * LW];
  __shared__ ushort lB[TN * LW];
  const int tile_m = blockIdx.x * 128;
  const int tile_n = blockIdx.y * TN;
  const int tid  = threadIdx.x;
  const int lane = tid & 63;
  const int w    = tid >> 6;
  const int wm = (w & 1) * 64;
  const int wn = (w >> 1) * TNW;
  f32x4 acc[4][NJ];
#pragma unroll
  for (int i = 0; i < 4; i++)
#pragma unroll
    for (int j = 0; j < NJ; j++) acc[i][j] = (f32x4){0.f, 0.f, 0.f, 0.f};

  // staging map: thread -> (row tid>>2 [+64], col (tid&3)*8)
  const int r0 = tid >> 2;
  const int c0 = (tid & 3) * 8;
  const ushort* agp0 = A + (size_t)(tile_m + r0) * lda + c0;
  const ushort* agp1 = A + (size_t)(tile_m + r0 + 64) * lda + c0;
  int bn0 = tile_n + r0;      if (bn0 > N - 1) bn0 = N - 1;
  const ushort* bgp0 = Bm + (size_t)bn0 * ldb + c0;
  const ushort* bgp1 = nullptr;
  if (TN == 128) {
    int bn1 = tile_n + r0 + 64; if (bn1 > N - 1) bn1 = N - 1;
    bgp1 = Bm + (size_t)bn1 * ldb + c0;
  }
  ushort* lA0 = lA + r0 * LW + c0;
  ushort* lA1 = lA + (r0 + 64) * LW + c0;
  ushort* lB0 = lB + r0 * LW + c0;
  ushort* lB1 = (TN == 128) ? (lB + (r0 + 64) * LW + c0) : nullptr;
  const int fm = lane & 15;
  const int fq = (lane >> 4) * 8;

  uint4 a0 = *(const uint4*)(agp0);
  uint4 a1 = *(const uint4*)(agp1);
  uint4 b0 = *(const uint4*)(bgp0);
  uint4 b1 = (TN == 128) ? *(const uint4*)(bgp1) : uint4{0, 0, 0, 0};
  for (int k0 = 0; k0 < K; k0 += 32) {
    __syncthreads();
    *(uint4*)lA0 = a0; *(uint4*)lA1 = a1;
    *(uint4*)lB0 = b0;
    if (TN == 128) *(uint4*)lB1 = b1;
    __syncthreads();
    int k1 = k0 + 32;
    if (k1 < K) {                       // prefetch next slab over compute
      a0 = *(const uint4*)(agp0 + k1);
      a1 = *(const uint4*)(agp1 + k1);
      b0 = *(const uint4*)(bgp0 + k1);
      if (TN == 128) b1 = *(const uint4*)(bgp1 + k1);
    }
    bf16x8 af[4], bfr[NJ];
#pragma unroll
    for (int i = 0; i < 4; i++)
      af[i]  = *(const bf16x8*)(lA + (wm + 16 * i + fm) * LW + fq);
#pragma unroll
    for (int j = 0; j < NJ; j++)
      bfr[j] = *(const bf16x8*)(lB + (wn + 16 * j + fm) * LW + fq);
#pragma unroll
    for (int i = 0; i < 4; i++)
#pragma unroll
      for (int j = 0; j < NJ; j++)
        acc[i][j] = __builtin_amdgcn_mfma_f32_16x16x32_bf16(af[i], bfr[j],
                                                            acc[i][j], 0, 0, 0);
  }

#pragma unroll
  for (int i = 0; i < 4; i++) {
#pragma unroll
    for (int j = 0; j < NJ; j++) {
      int col = tile_n + wn + 16 * j + (lane & 15);
      if (col >= N) continue;
      int row0 = tile_m + wm + 16 * i + (lane >> 4) * 4;
      float bv = (EPI == 1) ? 0.f : bias[col];
#pragma unroll
      for (int r = 0; r < 4; r++) {
        int row = row0 + r;
        float v = acc[i][j][r] + bv;
        if (EPI == 2) v = (v > 20.f) ? v : log1pf(__expf(v));
        if (EPI == 3) v += resid[(size_t)row * ldr + col];
        if constexpr (std::is_same<OT, float>::value)
          C[(size_t)row * ldc + col] = v;
        else
          C[(size_t)row * ldc + col] = f2bf(v);
      }
    }
  }
}

// ------------- 64x64 NT GEMM, register-prefetch staging, LW=40 -------------
template <int EPI, typename OT>
__global__ __launch_bounds__(256) void k_gemm(
    const ushort* __restrict__ A, int lda,
    const ushort* __restrict__ Bm, int ldb,
    int N, int K,
    const float* __restrict__ bias,
    const float* __restrict__ resid, int ldr,
    OT* __restrict__ C, int ldc) {
  constexpr int LW = 40;
  __shared__ ushort lA[64 * LW];
  __shared__ ushort lB[64 * LW];
  const int tile_m = blockIdx.x * 64;
  const int tile_n = blockIdx.y * 64;
  const int lane = threadIdx.x & 63;
  const int w    = threadIdx.x >> 6;
  const int wm = (w & 1) * 32;
  const int wn = (w >> 1) * 32;
  f32x4 acc[2][2];
#pragma unroll
  for (int i = 0; i < 2; i++)
#pragma unroll
    for (int j = 0; j < 2; j++) acc[i][j] = (f32x4){0.f, 0.f, 0.f, 0.f};

  const int arow = tile_m + w * 16 + (lane >> 2);
  int brow = tile_n + w * 16 + (lane >> 2);
  if (brow > N - 1) brow = N - 1;
  const int coff = (lane & 3) * 8;
  const ushort* ag = A  + (size_t)arow * lda + coff;
  const ushort* bg = Bm + (size_t)brow * ldb + coff;
  ushort* lAw = lA + (w * 16 + (lane >> 2)) * LW + coff;
  ushort* lBw = lB + (w * 16 + (lane >> 2)) * LW + coff;

  const int fm = lane & 15;
  const int fq = (lane >> 4) * 8;

  uint4 av = *(const uint4*)(ag);
  uint4 bv = *(const uint4*)(bg);
  for (int k0 = 0; k0 < K; k0 += 32) {
    __syncthreads();
    *(uint4*)lAw = av;
    *(uint4*)lBw = bv;
    __syncthreads();
    int k1 = k0 + 32;
    if (k1 < K) {
      av = *(const uint4*)(ag + k1);
      bv = *(const uint4*)(bg + k1);
    }
    bf16x8 a0 = *(const bf16x8*)(lA + (wm +  0 + fm) * LW + fq);
    bf16x8 a1 = *(const bf16x8*)(lA + (wm + 16 + fm) * LW + fq);
    bf16x8 b0 = *(const bf16x8*)(lB + (wn +  0 + fm) * LW + fq);
    bf16x8 b1 = *(const bf16x8*)(lB + (wn + 16 + fm) * LW + fq);
    acc[0][0] = __builtin_amdgcn_mfma_f32_16x16x32_bf16(a0, b0, acc[0][0], 0, 0, 0);
    acc[0][1] = __builtin_amdgcn_mfma_f32_16x16x32_bf16(a0, b1, acc[0][1], 0, 0, 0);
    acc[1][0] = __builtin_amdgcn_mfma_f32_16x16x32_bf16(a1, b0, acc[1][0], 0, 0, 0);
    acc[1][1] = __builtin_amdgcn_mfma_f32_16x16x32_bf16(a1, b1, acc[1][1], 0, 0, 0);
  }

#pragma unroll
  for (int mi = 0; mi < 2; mi++) {
#pragma unroll
    for (int ni = 0; ni < 2; ni++) {
      int col = tile_n + wn + ni * 16 + (lane & 15);
      if (col >= N) continue;
      int row0 = tile_m + wm + mi * 16 + (lane >> 4) * 4;
      float bv2 = (EPI == 1) ? 0.f : bias[col];
#pragma unroll
      for (int r = 0; r < 4; r++) {
        int row = row0 + r;
        float v = acc[mi][ni][r] + bv2;
        if (EPI == 2) v = (v > 20.f) ? v : log1pf(__expf(v));
        if (EPI == 3) v += resid[(size_t)row * ldr + col];
        if constexpr (std::is_same<OT, float>::value)
          C[(size_t)row * ldc + col] = v;
        else
          C[(size_t)row * ldc + col] = f2bf(v);
      }
    }
  }
}

// ------------- depthwise causal conv (k=4) + SiLU, 8 channels/thread -------
__global__ __launch_bounds__(256) void k_conv(const ushort* __restrict__ xz,
                                              const float* __restrict__ cw,
                                              const float* __restrict__ cb,
                                              ushort* __restrict__ xc) {
  int idx = blockIdx.x * 256 + threadIdx.x;   // over T_TOK * DI/8
  int d8 = (idx & 255) * 8;
  int t  = idx >> 8;
  int l  = t & 1023;
  float acc[8];
  {
    float4 c0 = *(const float4*)(cb + d8);
    float4 c1 = *(const float4*)(cb + d8 + 4);
    acc[0]=c0.x; acc[1]=c0.y; acc[2]=c0.z; acc[3]=c0.w;
    acc[4]=c1.x; acc[5]=c1.y; acc[6]=c1.z; acc[7]=c1.w;
  }
  float wk[8][4];
#pragma unroll
  for (int j = 0; j < 8; j++) {
    float4 wv = *(const float4*)(cw + (d8 + j) * 4);
    wk[j][0]=wv.x; wk[j][1]=wv.y; wk[j][2]=wv.z; wk[j][3]=wv.w;
  }
#pragma unroll
  for (int k = 0; k < 4; k++) {
    int lk = l + k - 3;
    if (lk >= 0) {
      uint4 raw = *(const uint4*)&xz[(size_t)(t + k - 3) * 4096 + d8];
      float v[8];
      v[0]=lo16(raw.x); v[1]=hi16(raw.x); v[2]=lo16(raw.y); v[3]=hi16(raw.y);
      v[4]=lo16(raw.z); v[5]=hi16(raw.z); v[6]=lo16(raw.w); v[7]=hi16(raw.w);
#pragma unroll
      for (int j = 0; j < 8; j++) acc[j] += v[j] * wk[j][k];
    }
  }
  uint32_t o[4];
#pragma unroll
  for (int p = 0; p < 4; p++) {
    float a0 = acc[2*p],   s0 = a0 / (1.f + __expf(-a0));
    float a1 = acc[2*p+1], s1 = a1 / (1.f + __expf(-a1));
    o[p] = (uint32_t)f2bf(s0) | ((uint32_t)f2bf(s1) << 16);
  }
  uint4 st = {o[0], o[1], o[2], o[3]};
  *(uint4*)&xc[(size_t)t * DI + d8] = st;
}

// ================= selective scan: chunked 3-phase (chunk=32) ==============
__global__ __launch_bounds__(256) void k_scan1(
    const ushort* __restrict__ dt,
    const ushort* __restrict__ xc,
    const ushort* __restrict__ xdbl,
    const float*  __restrict__ alog,
    float* __restrict__ P,
    float* __restrict__ Q)
{
  const int tid = threadIdx.x;
  const int d0  = blockIdx.x * 256;
  const int d   = d0 + tid;
  const int b   = blockIdx.y;
  const int c   = blockIdx.z;
  float Ac[16];
#pragma unroll
  for (int s = 0; s < 16; s++) Ac[s] = -__expf(alog[d * 16 + s]);
  float h[16];
#pragma unroll
  for (int s = 0; s < 16; s++) h[s] = 0.f;
  float sumdt = 0.f;
  __shared__ ushort s_dt[16][256];
  __shared__ ushort s_x [16][256];
  __shared__ ushort s_B [16][16];
  const int tok_c = b * 1024 + c * CL;
  for (int st = 0; st < CL; st += 16) {
    __syncthreads();
#pragma unroll
    for (int p = 0; p < 2; p++) {
      int idx = p * 256 + tid;
      int row = idx >> 5, col = (idx & 31) * 8;
      size_t goff = (size_t)(tok_c + st + row) * DI + d0 + col;
      *(uint4*)&s_dt[row][col] = *(const uint4*)&dt[goff];
      *(uint4*)&s_x [row][col] = *(const uint4*)&xc[goff];
    }
    s_B[tid >> 4][tid & 15] =
        xdbl[(size_t)(tok_c + st + (tid >> 4)) * XD + DTR + (tid & 15)];
    __syncthreads();
    for (int t = 0; t < 16; t++) {
      float dtv = bf2f(s_dt[t][tid]);
      float xv  = bf2f(s_x [t][tid]);
      float dtx = dtv * xv;
      sumdt += dtv;
      uint4 b0 = *(const uint4*)&s_B[t][0];
      uint4 b1 = *(const uint4*)&s_B[t][8];
      float Bf[16];
      Bf[0]=lo16(b0.x); Bf[1]=hi16(b0.x); Bf[2]=lo16(b0.y); Bf[3]=hi16(b0.y);
      Bf[4]=lo16(b0.z); Bf[5]=hi16(b0.z); Bf[6]=lo16(b0.w); Bf[7]=hi16(b0.w);
      Bf[8]=lo16(b1.x); Bf[9]=hi16(b1.x); Bf[10]=lo16(b1.y); Bf[11]=hi16(b1.y);
      Bf[12]=lo16(b1.z); Bf[13]=hi16(b1.z); Bf[14]=lo16(b1.w); Bf[15]=hi16(b1.w);
#pragma unroll
      for (int s = 0; s < 16; s++) {
        float dA = __expf(dtv * Ac[s]);
        h[s] = dA * h[s] + dtx * Bf[s];
      }
    }
  }
  size_t base = (((size_t)(b * NCH + c)) * 2048 + d) * 16;
#pragma unroll
  for (int s = 0; s < 16; s++) {
    P[base + s] = __expf(sumdt * Ac[s]);
    Q[base + s] = h[s];
  }
}

__global__ __launch_bounds__(256) void k_carry(const float* __restrict__ P,
                                               float* __restrict__ Q) {
  int tid = blockIdx.x * 256 + threadIdx.x;   // 65536 = 2*2048*16
  int ds = tid & 32767, b = tid >> 15;
  float Pc[NCH], Qc[NCH];
#pragma unroll
  for (int c = 0; c < NCH; c++) {
    size_t idx = ((size_t)(b * NCH + c)) * 32768 + ds;
    Pc[c] = P[idx];
    Qc[c] = Q[idx];
  }
  float H = 0.f;
#pragma unroll
  for (int c = 0; c < NCH; c++) {
    size_t idx = ((size_t)(b * NCH + c)) * 32768 + ds;
    Q[idx] = H;
    H = Pc[c] * H + Qc[c];
  }
}

__global__ __launch_bounds__(256) void k_scan2(
    const ushort* __restrict__ dt,
    const ushort* __restrict__ xc,
    const ushort* __restrict__ xdbl,
    const ushort* __restrict__ xz,
    const float*  __restrict__ alog,
    const float*  __restrict__ Dp,
    const float*  __restrict__ Hin,
    ushort* __restrict__ yg)
{
  const int tid = threadIdx.x;
  const int d0  = blockIdx.x * 256;
  const int d   = d0 + tid;
  const int b   = blockIdx.y;
  const int c   = blockIdx.z;
  float Ac[16];
#pragma unroll
  for (int s = 0; s < 16; s++) Ac[s] = -__expf(alog[d * 16 + s]);
  float h[16];
  size_t hbase = (((size_t)(b * NCH + c)) * 2048 + d) * 16;
#pragma unroll
  for (int s = 0; s < 16; s++) h[s] = Hin[hbase + s];
  const float Dv = Dp[d];
  __shared__ ushort s_dt[16][256];
  __shared__ ushort s_x [16][256];
  __shared__ ushort s_z [16][256];
  __shared__ ushort s_B [16][16];
  __shared__ ushort s_C [16][16];
  const int tok_c = b * 1024 + c * CL;
  for (int st = 0; st < CL; st += 16) {
    __syncthreads();
#pragma unroll
    for (int p = 0; p < 2; p++) {
      int idx = p * 256 + tid;
      int row = idx >> 5, col = (idx & 31) * 8;
      size_t tok = (size_t)(tok_c + st + row);
      *(uint4*)&s_dt[row][col] = *(const uint4*)&dt[tok * DI + d0 + col];
      *(uint4*)&s_x [row][col] = *(const uint4*)&xc[tok * DI + d0 + col];
      *(uint4*)&s_z [row][col] = *(const uint4*)&xz[tok * 4096 + DI + d0 + col];
    }
    {
      int t = tid >> 4, s = tid & 15;
      size_t tok = (size_t)(tok_c + st + t);
      s_B[t][s] = xdbl[tok * XD + DTR + s];
      s_C[t][s] = xdbl[tok * XD + DTR + NST + s];
    }
    __syncthreads();
    for (int t = 0; t < 16; t++) {
      float dtv = bf2f(s_dt[t][tid]);
      float xv  = bf2f(s_x [t][tid]);
      float zv  = bf2f(s_z [t][tid]);
      float dtx = dtv * xv;
      uint4 b0 = *(const uint4*)&s_B[t][0];
      uint4 b1 = *(const uint4*)&s_B[t][8];
      uint4 c0 = *(const uint4*)&s_C[t][0];
      uint4 c1 = *(const uint4*)&s_C[t][8];
      float Bf[16], Cf[16];
      Bf[0]=lo16(b0.x); Bf[1]=hi16(b0.x); Bf[2]=lo16(b0.y); Bf[3]=hi16(b0.y);
      Bf[4]=lo16(b0.z); Bf[5]=hi16(b0.z); Bf[6]=lo16(b0.w); Bf[7]=hi16(b0.w);
      Bf[8]=lo16(b1.x); Bf[9]=hi16(b1.x); Bf[10]=lo16(b1.y); Bf[11]=hi16(b1.y);
      Bf[12]=lo16(b1.z); Bf[13]=hi16(b1.z); Bf[14]=lo16(b1.w); Bf[15]=hi16(b1.w);
      Cf[0]=lo16(c0.x); Cf[1]=hi16(c0.x); Cf[2]=lo16(c0.y); Cf[3]=hi16(c0.y);
      Cf[4]=lo16(c0.z); Cf[5]=hi16(c0.z); Cf[6]=lo16(c0.w); Cf[7]=hi16(c0.w);
      Cf[8]=lo16(c1.x); Cf[9]=hi16(c1.x); Cf[10]=lo16(c1.y); Cf[11]=hi16(c1.y);
      Cf[12]=lo16(c1.z); Cf[13]=hi16(c1.z); Cf[14]=lo16(c1.w); Cf[15]=hi16(c1.w);
      float y = 0.f;
#pragma unroll
      for (int s = 0; s < 16; s++) {
        float dA = __expf(dtv * Ac[s]);
        h[s] = dA * h[s] + dtx * Bf[s];
        y += h[s] * Cf[s];
      }
      y = (y + Dv * xv) * (zv / (1.f + __expf(-zv)));
      yg[(size_t)(tok_c + st + t) * DI + d] = f2bf(y);
    }
  }
}

extern "C" void kernel_launch(void* const* d_in, const int* in_sizes, int n_in,
                              void* d_out, int out_size, void* d_ws, size_t ws_size,
                              hipStream_t stream) {
  const float* x     = (const float*)d_in[0];
  const float* ln_g  = (const float*)d_in[1];
  const float* ln_b  = (const float*)d_in[2];
  const float* W_in  = (const float*)d_in[3];
  const float* b_in  = (const float*)d_in[4];
  const float* cw    = (const float*)d_in[5];
  const float* cb    = (const float*)d_in[6];
  const float* W_x   = (const float*)d_in[7];
  const float* W_dt  = (const float*)d_in[8];
  const float* b_dt  = (const float*)d_in[9];
  const float* A_log = (const float*)d_in[10];
  const float* Dp    = (const float*)d_in[11];
  const float* W_out = (const float*)d_in[12];
  const float* b_out = (const float*)d_in[13];
  float* out = (float*)d_out;

  const int nWin  = 2 * DI * DM;
  const int nWx   = XD * DI;
  const int nWdt  = DI * DTR;
  const int nWout = DM * DI;
  const int nWtot = nWin + nWx + nWdt + nWout;   // 6,619,136 = 6464*1024

  char* ws = (char*)d_ws;
  ushort* wbf  = (ushort*)(ws);
  ushort* wWin  = wbf;
  ushort* wWx   = wbf + nWin;
  ushort* wWdt  = wbf + nWin + nWx;
  ushort* wWout = wbf + nWin + nWx + nWdt;
  ushort* xn   = (ushort*)(ws + 16u * 1024 * 1024);   // 4 MB
  ushort* xz   = (ushort*)(ws + 24u * 1024 * 1024);   // 16 MB
  ushort* xc   = (ushort*)(ws + 40u * 1024 * 1024);   // 8 MB
  ushort* xdbl = (ushort*)(ws + 48u * 1024 * 1024);   // 0.4 MB
  ushort* dtb  = (ushort*)(ws + 52u * 1024 * 1024);   // 8 MB
  ushort* ygb  = (ushort*)(ws + 60u * 1024 * 1024);   // 8 MB
  float*  Pbuf = (float*)(ws + 68u * 1024 * 1024);    // 8 MB (2*32*2048*16 f32)
  float*  Qbuf = (float*)(ws + 76u * 1024 * 1024);    // 8 MB (total 84 MB)

  k_prep<<<CAST_BLK + T_TOK, 256, 0, stream>>>(W_in, nWin, W_x, nWx, W_dt, nWdt,
                                               W_out, nWout, wbf,
                                               x, ln_g, ln_b, xn);
  // xz = xn @ W_in^T + b_in            [2048 x 4096], K=1024 -> 512 blocks
  k_gemm128<0, ushort, 128><<<dim3(16, 32), 256, 0, stream>>>(
      xn, DM, wWin, DM, 2 * DI, DM, b_in, nullptr, 0, xz, 2 * DI);
  k_conv<<<(T_TOK * DI / 8) / 256, 256, 0, stream>>>(xz, cw, cb, xc);
  // xdbl = xc @ W_x^T                  [2048 x 96], K=2048
  k_gemm<1, ushort><<<dim3(32, 2), 256, 0, stream>>>(xc, DI, wWx, DI, XD, DI,
                                                     nullptr, nullptr, 0, xdbl, XD);
  // dt = softplus(xdbl[:, :64] @ W_dt^T + b_dt)   [2048 x 2048], K=64
  k_gemm<2, ushort><<<dim3(32, 32), 256, 0, stream>>>(xdbl, XD, wWdt, DTR, DI, DTR,
                                                      b_dt, nullptr, 0, dtb, DI);
  // chunked selective scan (32 chunks of 32 steps)
  k_scan1<<<dim3(8, 2, NCH), 256, 0, stream>>>(dtb, xc, xdbl, A_log, Pbuf, Qbuf);
  k_carry<<<256, 256, 0, stream>>>(Pbuf, Qbuf);
  k_scan2<<<dim3(8, 2, NCH), 256, 0, stream>>>(dtb, xc, xdbl, xz, A_log, Dp,
                                               Qbuf, ygb);
  // out = ygb @ W_out^T + b_out + x    [2048 x 1024], K=2048 -> 256 blocks
  k_gemm128<3, float, 64><<<dim3(16, 16), 256, 0, stream>>>(
      ygb, DI, wWout, DI, DM, DI, b_out, x, DM, out, DM);
}